// Round 1
// baseline (351.221 us; speedup 1.0000x reference)
//
#include <hip/hip_runtime.h>

namespace {
constexpr int Hn = 512, Wn = 512, Cn = 32, Gn = 16;
constexpr int WHn = 227, WWn = 227;
constexpr int OHn = Hn - WHn;   // 285
constexpr int OWn = Wn - WWn;   // 285
constexpr int PTn = (Hn - OHn) / 2;  // 113
constexpr int PLn = (Wn - OWn) / 2;  // 113
constexpr float EPSn = 1e-5f;
}

// One block per (n, g, row-half). 512 threads = one per column.
// Vertical 227-row sliding window in double-precision registers;
// horizontal 227-col window via 512-wide inclusive prefix scan in LDS.
// Window for stat (h,w) covers input rows h+1..h+227, cols w+1..w+227
// (matches reference ii[wh:]-ii[:-wh] convention).
__global__ __launch_bounds__(512) void lcn_stats(const float* __restrict__ x,
                                                 float2* __restrict__ stats) {
  const int blk = blockIdx.x;
  const int half = blk & 1;
  const int ng = blk >> 1;          // n*16 + g
  const int n = ng >> 4;
  const int g = ng & 15;
  const int w = threadIdx.x;

  const float* __restrict__ x0 = x + (size_t)(n * Cn + g * 2) * Hn * Wn;
  const float* __restrict__ x1 = x0 + (size_t)Hn * Wn;

  const int h0 = half ? 142 : 0;
  const int h1 = half ? OHn : 142;

  double accS = 0.0, accQ = 0.0;
  // ramp: rows h0+1 .. h0+227
  for (int r = h0 + 1; r <= h0 + WHn; ++r) {
    float a = x0[(size_t)r * Wn + w];
    float b = x1[(size_t)r * Wn + w];
    accS += (double)a + (double)b;
    accQ += (double)a * (double)a + (double)b * (double)b;
  }

  __shared__ float2 Pbuf[Wn + 1];   // Pbuf[j+1] = inclusive prefix of cols 0..j
  __shared__ float2 wsum[8];
  const float inv_n = 1.0f / (float)(WHn * WWn * 2);
  const int lane = w & 63;
  const int wid = w >> 6;

  for (int h = h0;;) {
    float2 v = make_float2((float)accS, (float)accQ);
    // intra-wave inclusive scan (64 lanes)
    #pragma unroll
    for (int d = 1; d < 64; d <<= 1) {
      float sx = __shfl_up(v.x, d, 64);
      float sy = __shfl_up(v.y, d, 64);
      if (lane >= d) { v.x += sx; v.y += sy; }
    }
    if (lane == 63) wsum[wid] = v;
    __syncthreads();
    if (w == 0) {
      float2 run = make_float2(0.f, 0.f);
      #pragma unroll
      for (int i = 0; i < 8; ++i) {
        float2 t = wsum[i];
        wsum[i] = run;
        run.x += t.x; run.y += t.y;
      }
    }
    __syncthreads();
    float2 off = wsum[wid];
    Pbuf[w + 1] = make_float2(v.x + off.x, v.y + off.y);
    __syncthreads();
    if (w < OWn) {
      // cols w+1..w+227 = P[w+228] - P[w+1]  (Pbuf shifted by +1)
      float2 hi = Pbuf[w + WWn + 1];
      float2 lo = Pbuf[w + 1];
      float S = hi.x - lo.x;
      float Q = hi.y - lo.y;
      float mean = S * inv_n;
      float var = (Q - S * S * inv_n) * inv_n;
      float istd = rsqrtf(var + EPSn);
      stats[((size_t)ng * OHn + h) * OWn + w] = make_float2(mean, istd);
    }
    if (++h >= h1) break;
    {
      // slide: add row h+227, subtract row h
      const size_t ra = (size_t)(h + WHn) * Wn + w;
      const size_t rs = (size_t)h * Wn + w;
      float a0 = x0[ra], a1 = x1[ra];
      float s0 = x0[rs], s1 = x1[rs];
      accS += ((double)a0 + (double)a1) - ((double)s0 + (double)s1);
      accQ += ((double)a0 * a0 + (double)a1 * a1)
            - ((double)s0 * s0 + (double)s1 * s1);
    }
    __syncthreads();   // protect Pbuf/wsum before next iteration rewrites
  }
}

// out = (x - mean) * invstd * weight[c] + bias[c], float4-vectorized.
__global__ __launch_bounds__(256) void lcn_norm(const float* __restrict__ x,
                                                const float* __restrict__ weight,
                                                const float* __restrict__ bias,
                                                const float2* __restrict__ stats,
                                                float* __restrict__ out) {
  const size_t idx = (size_t)blockIdx.x * blockDim.x + threadIdx.x; // float4 id
  const int w4 = (int)(idx & (Wn / 4 - 1));       // 0..127
  const size_t row = idx >> 7;                    // (n*32+c)*512 + hh
  const int hh = (int)(row & (Hn - 1));
  const int c = (int)((row >> 9) & (Cn - 1));
  const int n = (int)(row >> 14);
  const int g = c >> 1;

  const int hp = min(max(hh - PTn, 0), OHn - 1);
  const float2* __restrict__ srow =
      stats + ((size_t)(n * Gn + g) * OHn + hp) * OWn;
  const float wt = weight[c];
  const float bs = bias[c];

  const float4 xv = reinterpret_cast<const float4*>(x)[idx];
  float4 ov;
  const int wwb = w4 * 4;
  {
    int wp = min(max(wwb + 0 - PLn, 0), OWn - 1);
    float2 mv = srow[wp];
    ov.x = (xv.x - mv.x) * mv.y * wt + bs;
  }
  {
    int wp = min(max(wwb + 1 - PLn, 0), OWn - 1);
    float2 mv = srow[wp];
    ov.y = (xv.y - mv.x) * mv.y * wt + bs;
  }
  {
    int wp = min(max(wwb + 2 - PLn, 0), OWn - 1);
    float2 mv = srow[wp];
    ov.z = (xv.z - mv.x) * mv.y * wt + bs;
  }
  {
    int wp = min(max(wwb + 3 - PLn, 0), OWn - 1);
    float2 mv = srow[wp];
    ov.w = (xv.w - mv.x) * mv.y * wt + bs;
  }
  reinterpret_cast<float4*>(out)[idx] = ov;
}

extern "C" void kernel_launch(void* const* d_in, const int* in_sizes, int n_in,
                              void* d_out, int out_size, void* d_ws, size_t ws_size,
                              hipStream_t stream) {
  const float* x = (const float*)d_in[0];
  const float* weight = (const float*)d_in[1];
  const float* bias = (const float*)d_in[2];
  float* out = (float*)d_out;
  float2* stats = (float2*)d_ws;  // needs 128*285*285*8 = 83,174,400 B

  hipLaunchKernelGGL(lcn_stats, dim3(256), dim3(512), 0, stream, x, stats);

  const int total4 = (8 * Cn * Hn * Wn) / 4;      // 16,777,216 float4s
  hipLaunchKernelGGL(lcn_norm, dim3(total4 / 256), dim3(256), 0, stream,
                     x, weight, bias, stats, out);
}

// Round 2
// 248.318 us; speedup vs baseline: 1.4144x; 1.4144x over previous
//
#include <hip/hip_runtime.h>

namespace {
constexpr int Hn = 512, Wn = 512, Cn = 32, Gn = 16;
constexpr int WHn = 227, WWn = 227;
constexpr int OHn = Hn - WHn;        // 285
constexpr int OWn = Wn - WWn;        // 285
constexpr int PTn = (Hn - OHn) / 2;  // 113
constexpr int PLn = (Wn - OWn) / 2;  // 113
constexpr float EPSn = 1e-5f;
constexpr int CHUNKS = 4;            // row-chunks per (n,g) -> 512 blocks
constexpr int RPC = 72;              // rows per chunk (last chunk: 69)
}

// One block per (n, g, chunk-of-rows). 512 threads = one per column.
// Vertical 227-row sliding window in double registers; 4 output rows per
// iteration share one scan-section (3 barriers / 4 rows). Slide-row loads
// for the NEXT iteration are issued before this iteration's scan so HBM
// latency hides under scan+barrier time.
// Window for stat (h,w): input rows h+1..h+227, cols w+1..w+227.
__global__ __launch_bounds__(512, 4) void lcn_stats(const float* __restrict__ x,
                                                    float2* __restrict__ stats) {
  const int blk = blockIdx.x;
  const int chunk = blk & (CHUNKS - 1);
  const int ng = blk / CHUNKS;       // n*16 + g
  const int n = ng >> 4;
  const int g = ng & 15;
  const int w = threadIdx.x;
  const int lane = w & 63;
  const int wid = w >> 6;

  const float* __restrict__ x0 = x + (size_t)(n * Cn + g * 2) * Hn * Wn;
  const float* __restrict__ x1 = x0 + (size_t)Hn * Wn;

  const int h0 = chunk * RPC;
  const int h1 = min(OHn, h0 + RPC);

  // ---- ramp: rows h0+1 .. h0+227, two partial accumulators for ILP ----
  double sA = 0.0, sB = 0.0, qA = 0.0, qB = 0.0;
  for (int r = h0 + 1; r + 1 <= h0 + WHn; r += 2) {
    float a = x0[(size_t)r * Wn + w];
    float b = x1[(size_t)r * Wn + w];
    float c = x0[(size_t)(r + 1) * Wn + w];
    float d = x1[(size_t)(r + 1) * Wn + w];
    sA += (double)a + (double)b;
    qA += (double)a * a + (double)b * b;
    sB += (double)c + (double)d;
    qB += (double)c * c + (double)d * d;
  }
  {
    float a = x0[(size_t)(h0 + WHn) * Wn + w];
    float b = x1[(size_t)(h0 + WHn) * Wn + w];
    sA += (double)a + (double)b;
    qA += (double)a * a + (double)b * b;
  }
  double accS = sA + sB, accQ = qA + qB;

  __shared__ float2 Ps[4][Wn + 1];   // Ps[r][j+1] = inclusive prefix cols 0..j
  __shared__ float2 wsum[8][4];
  const float inv_n = 1.0f / (float)(WHn * WWn * 2);

  // prefetch registers: add rows h+228+j, sub rows h+1+j (j=0..3), 2 channels
  float pa0[4], pa1[4], ps0[4], ps1[4];
  auto prefetch = [&](int hb) {
    #pragma unroll
    for (int j = 0; j < 4; ++j) {
      int ra = min(hb + WHn + 1 + j, Hn - 1);   // clamp: OOB rows are unused
      int rs = hb + 1 + j;                      // always <= 288 < 512
      pa0[j] = x0[(size_t)ra * Wn + w];
      pa1[j] = x1[(size_t)ra * Wn + w];
      ps0[j] = x0[(size_t)rs * Wn + w];
      ps1[j] = x1[(size_t)rs * Wn + w];
    }
  };
  prefetch(h0);

  for (int h = h0; h < h1; h += 4) {
    // ---- consume prefetched rows: v[r] = window(h+r), accNext = window(h+4)
    float2 v[4];
    v[0] = make_float2((float)accS, (float)accQ);
    double s = accS, q = accQ;
    #pragma unroll
    for (int j = 0; j < 3; ++j) {
      s += ((double)pa0[j] + (double)pa1[j]) - ((double)ps0[j] + (double)ps1[j]);
      q += ((double)pa0[j] * pa0[j] + (double)pa1[j] * pa1[j])
         - ((double)ps0[j] * ps0[j] + (double)ps1[j] * ps1[j]);
      v[j + 1] = make_float2((float)s, (float)q);
    }
    s += ((double)pa0[3] + (double)pa1[3]) - ((double)ps0[3] + (double)ps1[3]);
    q += ((double)pa0[3] * pa0[3] + (double)pa1[3] * pa1[3])
       - ((double)ps0[3] * ps0[3] + (double)ps1[3] * ps1[3]);
    accS = s; accQ = q;

    // ---- issue next iteration's loads now; latency hides under the scan ----
    if (h + 4 < h1) prefetch(h + 4);

    // ---- 4 independent 512-wide inclusive scans (shared barriers) ----
    #pragma unroll
    for (int d = 1; d < 64; d <<= 1) {
      #pragma unroll
      for (int r = 0; r < 4; ++r) {
        float sx = __shfl_up(v[r].x, d, 64);
        float sy = __shfl_up(v[r].y, d, 64);
        if (lane >= d) { v[r].x += sx; v[r].y += sy; }
      }
    }
    if (lane == 63) {
      #pragma unroll
      for (int r = 0; r < 4; ++r) wsum[wid][r] = v[r];
    }
    __syncthreads();
    float2 off[4] = {{0.f,0.f},{0.f,0.f},{0.f,0.f},{0.f,0.f}};
    #pragma unroll
    for (int i = 0; i < 7; ++i) {
      if (i < wid) {
        #pragma unroll
        for (int r = 0; r < 4; ++r) {
          off[r].x += wsum[i][r].x; off[r].y += wsum[i][r].y;
        }
      }
    }
    #pragma unroll
    for (int r = 0; r < 4; ++r)
      Ps[r][w + 1] = make_float2(v[r].x + off[r].x, v[r].y + off[r].y);
    __syncthreads();

    if (w < OWn) {
      #pragma unroll
      for (int r = 0; r < 4; ++r) {
        if (h + r < h1) {
          float2 hi = Ps[r][w + WWn + 1];
          float2 lo = Ps[r][w + 1];
          float S = hi.x - lo.x;
          float Q = hi.y - lo.y;
          float mean = S * inv_n;
          float var = (Q - S * S * inv_n) * inv_n;
          float istd = rsqrtf(var + EPSn);
          stats[((size_t)ng * OHn + (h + r)) * OWn + w] = make_float2(mean, istd);
        }
      }
    }
    __syncthreads();   // protect Ps/wsum before next iteration rewrites
  }
}

// out = (x - mean) * invstd * weight[c] + bias[c], float4-vectorized.
__global__ __launch_bounds__(256) void lcn_norm(const float* __restrict__ x,
                                                const float* __restrict__ weight,
                                                const float* __restrict__ bias,
                                                const float2* __restrict__ stats,
                                                float* __restrict__ out) {
  const size_t idx = (size_t)blockIdx.x * blockDim.x + threadIdx.x; // float4 id
  const int w4 = (int)(idx & (Wn / 4 - 1));       // 0..127
  const size_t row = idx >> 7;                    // (n*32+c)*512 + hh
  const int hh = (int)(row & (Hn - 1));
  const int c = (int)((row >> 9) & (Cn - 1));
  const int n = (int)(row >> 14);
  const int g = c >> 1;

  const int hp = min(max(hh - PTn, 0), OHn - 1);
  const float2* __restrict__ srow =
      stats + ((size_t)(n * Gn + g) * OHn + hp) * OWn;
  const float wt = weight[c];
  const float bs = bias[c];

  const float4 xv = reinterpret_cast<const float4*>(x)[idx];
  float4 ov;
  const int wwb = w4 * 4;
  {
    int wp = min(max(wwb + 0 - PLn, 0), OWn - 1);
    float2 mv = srow[wp];
    ov.x = (xv.x - mv.x) * mv.y * wt + bs;
  }
  {
    int wp = min(max(wwb + 1 - PLn, 0), OWn - 1);
    float2 mv = srow[wp];
    ov.y = (xv.y - mv.x) * mv.y * wt + bs;
  }
  {
    int wp = min(max(wwb + 2 - PLn, 0), OWn - 1);
    float2 mv = srow[wp];
    ov.z = (xv.z - mv.x) * mv.y * wt + bs;
  }
  {
    int wp = min(max(wwb + 3 - PLn, 0), OWn - 1);
    float2 mv = srow[wp];
    ov.w = (xv.w - mv.x) * mv.y * wt + bs;
  }
  reinterpret_cast<float4*>(out)[idx] = ov;
}

extern "C" void kernel_launch(void* const* d_in, const int* in_sizes, int n_in,
                              void* d_out, int out_size, void* d_ws, size_t ws_size,
                              hipStream_t stream) {
  const float* x = (const float*)d_in[0];
  const float* weight = (const float*)d_in[1];
  const float* bias = (const float*)d_in[2];
  float* out = (float*)d_out;
  float2* stats = (float2*)d_ws;  // needs 128*285*285*8 = 83,174,400 B

  hipLaunchKernelGGL(lcn_stats, dim3(128 * CHUNKS), dim3(512), 0, stream,
                     x, stats);

  const int total4 = (8 * Cn * Hn * Wn) / 4;      // 16,777,216 float4s
  hipLaunchKernelGGL(lcn_norm, dim3(total4 / 256), dim3(256), 0, stream,
                     x, weight, bias, stats, out);
}